// Round 1
// baseline (335.967 us; speedup 1.0000x reference)
//
#include <hip/hip_runtime.h>
#include <hip/hip_bf16.h>

typedef __attribute__((ext_vector_type(8))) __bf16 bf16x8;
typedef __attribute__((ext_vector_type(4))) float f32x4;

#if __has_builtin(__builtin_amdgcn_exp2f)
#define EXP2F(x) __builtin_amdgcn_exp2f(x)
#else
#define EXP2F(x) exp2f(x)
#endif

static constexpr int BB = 8, CC = 64, NN = 4096;

// float-offsets into workspace
static constexpr size_t OFF_WQKT = 0;                          // 64*16 : [c][8 q-scaled | 8 k]
static constexpr size_t OFF_BQK  = 1024;                       // 16
static constexpr size_t OFF_WVT  = 1040;                       // 64*64 : Wv^T [c][o]
static constexpr size_t OFF_BV   = 5136;                       // 64
static constexpr size_t OFF_QF   = 8192;                       // B*N*8 fp32 (log2e-scaled q)
static constexpr size_t OFF_KF   = OFF_QF + (size_t)BB*NN*8;   // B*N*8 fp32
static constexpr size_t OFF_VB_F = OFF_KF + (size_t)BB*NN*8;   // here: bf16 [B][C][N]
// total ws: ~6.03 MB

__global__ __launch_bounds__(256) void prep_kernel(
    const float* __restrict__ Wq, const float* __restrict__ bq,
    const float* __restrict__ Wk, const float* __restrict__ bk,
    const float* __restrict__ Wv, const float* __restrict__ bv,
    float* __restrict__ ws) {
  const float LOG2E = 1.4426950408889634f;
  int t = threadIdx.x;
  float* wqkT = ws + OFF_WQKT;
  float* bqk  = ws + OFF_BQK;
  float* wvT  = ws + OFF_WVT;
  float* bvv  = ws + OFF_BV;
  for (int idx = t; idx < 512; idx += 256) {
    int c = idx >> 3, o = idx & 7;
    wqkT[c*16 + o]     = Wq[o*64 + c] * LOG2E;   // fold log2e into q-weights
    wqkT[c*16 + 8 + o] = Wk[o*64 + c];
  }
  for (int idx = t; idx < 4096; idx += 256) {
    int c = idx >> 6, o = idx & 63;
    wvT[c*64 + o] = Wv[o*64 + c];
  }
  if (t < 8)            bqk[t] = bq[t] * LOG2E;
  else if (t < 16)      bqk[t] = bk[t - 8];
  if (t < 64)           bvv[t] = bv[t];
}

// One thread per pixel: q/k/v projections. Weights read via wave-uniform
// (scalar) loads from transposed copies; input reads coalesced along pixels.
__global__ __launch_bounds__(256) void proj_kernel(
    const float* __restrict__ query, const float* __restrict__ value,
    float* __restrict__ ws) {
  const float* wqkT = ws + OFF_WQKT;
  const float* bqk  = ws + OFF_BQK;
  const float* wvT  = ws + OFF_WVT;
  const float* bvv  = ws + OFF_BV;
  float* qf = ws + OFF_QF;
  float* kf = ws + OFF_KF;
  __bf16* vb = (__bf16*)(ws + OFF_VB_F);

  int t = blockIdx.x * 256 + threadIdx.x;          // t = b*4096 + pix
  size_t base_in = ((size_t)(t >> 12)) * CC * NN + (size_t)(t & 4095);

  float qacc[8], kacc[8], vacc[64];
  #pragma unroll
  for (int o = 0; o < 8; ++o) { qacc[o] = bqk[o]; kacc[o] = bqk[8 + o]; }
  #pragma unroll
  for (int o = 0; o < 64; ++o) vacc[o] = bvv[o];

  for (int c = 0; c < 64; ++c) {
    float xq = query[base_in + (size_t)c * NN];
    float xv = value[base_in + (size_t)c * NN];
    const float* wq = wqkT + c * 16;
    #pragma unroll
    for (int o = 0; o < 8; ++o) {
      qacc[o] += wq[o] * xq;
      kacc[o] += wq[8 + o] * xq;
    }
    const float* wv = wvT + c * 64;
    #pragma unroll
    for (int o = 0; o < 64; ++o) vacc[o] += wv[o] * xv;
  }

  float* qo = qf + (size_t)t * 8;   // [b][pix][8], coalesced 32B/lane
  float* ko = kf + (size_t)t * 8;
  #pragma unroll
  for (int o = 0; o < 8; ++o) { qo[o] = qacc[o]; ko[o] = kacc[o]; }
  __bf16* vo = vb + ((size_t)(t >> 12)) * CC * NN + (size_t)(t & 4095);
  #pragma unroll
  for (int o = 0; o < 64; ++o) vo[(size_t)o * NN] = (__bf16)vacc[o];
}

// One wave per 16 query rows. Lane (ip=lane&15, qd=lane>>4).
// Energy in fp32 (lane computes S[ip][qd*8+r] for the 32-j k-step), exp2,
// result is ALREADY in mfma B-operand layout (n=lane&15, k=quad*8+r).
// A-operand = V bf16 [C][N] loaded straight from global (m=lane&15 -> c).
// D[c][i]: row=(lane>>4)*4+reg -> c, col=lane&15 -> i.
__global__ __launch_bounds__(256) void attn_kernel(
    const float* __restrict__ ws, const float* __restrict__ value,
    float* __restrict__ out) {
  const float* qf = ws + OFF_QF;
  const float* kf = ws + OFF_KF;
  const __bf16* vb = (const __bf16*)(ws + OFF_VB_F);

  int lane = threadIdx.x & 63;
  int wv   = threadIdx.x >> 6;
  int g    = blockIdx.x * 4 + wv;      // global wave id, 0..2047
  int b    = g >> 8;                   // 256 i-tiles per batch
  int i0   = (g & 255) << 4;
  int ip   = lane & 15;
  int qd   = lane >> 4;

  const float* qrow = qf + (((size_t)b * NN) + i0 + ip) * 8;
  float4 qa = *(const float4*)qrow;
  float4 qb = *(const float4*)(qrow + 4);

  const float* kbase  = kf + (size_t)b * NN * 8;
  const __bf16* vbase = vb + (size_t)b * CC * NN;

  f32x4 acc[4];
  #pragma unroll
  for (int ct = 0; ct < 4; ++ct) acc[ct] = (f32x4){0.f, 0.f, 0.f, 0.f};
  float l = 0.f;

  for (int m0 = 0; m0 < NN; m0 += 32) {
    int jbase = m0 + qd * 8;
    const float* kr = kbase + (size_t)jbase * 8;
    bf16x8 pfrag;
    #pragma unroll
    for (int r = 0; r < 8; ++r) {
      float4 ka = *(const float4*)(kr + r * 8);
      float4 kb = *(const float4*)(kr + r * 8 + 4);
      float s = qa.x * ka.x + qa.y * ka.y + qa.z * ka.z + qa.w * ka.w
              + qb.x * kb.x + qb.y * kb.y + qb.z * kb.z + qb.w * kb.w;
      float p = EXP2F(s);      // q pre-scaled by log2e -> this is e^energy
      l += p;
      pfrag[r] = (__bf16)p;
    }
    #pragma unroll
    for (int ct = 0; ct < 4; ++ct) {
      const __bf16* va = vbase + ((size_t)(ct * 16 + ip)) * NN + jbase;
      bf16x8 afrag = *(const bf16x8*)va;   // 16B aligned: jbase % 8 == 0
      acc[ct] = __builtin_amdgcn_mfma_f32_16x16x32_bf16(afrag, pfrag, acc[ct], 0, 0, 0);
    }
  }

  // softmax denominator: lanes {ip, ip+16, ip+32, ip+48} hold disjoint j-subsets
  l += __shfl_xor(l, 16, 64);
  l += __shfl_xor(l, 32, 64);
  float inv = 1.0f / l;

  int n = i0 + ip;
  #pragma unroll
  for (int ct = 0; ct < 4; ++ct) {
    #pragma unroll
    for (int r = 0; r < 4; ++r) {
      int c = ct * 16 + qd * 4 + r;
      size_t idx = ((size_t)b * CC + c) * NN + n;
      out[idx] = acc[ct][r] * inv + value[idx];
    }
  }
}

extern "C" void kernel_launch(void* const* d_in, const int* in_sizes, int n_in,
                              void* d_out, int out_size, void* d_ws, size_t ws_size,
                              hipStream_t stream) {
  const float* query = (const float*)d_in[0];
  const float* value = (const float*)d_in[1];
  const float* Wq = (const float*)d_in[2];
  const float* bq = (const float*)d_in[3];
  const float* Wk = (const float*)d_in[4];
  const float* bk = (const float*)d_in[5];
  const float* Wv = (const float*)d_in[6];
  const float* bv = (const float*)d_in[7];
  float* ws  = (float*)d_ws;
  float* out = (float*)d_out;

  prep_kernel<<<1, 256, 0, stream>>>(Wq, bq, Wk, bk, Wv, bv, ws);
  proj_kernel<<<BB * NN / 256, 256, 0, stream>>>(query, value, ws);
  attn_kernel<<<BB * NN / 16 / 4, 256, 0, stream>>>(ws, value, out);
}

// Round 2
// 156.705 us; speedup vs baseline: 2.1440x; 2.1440x over previous
//
#include <hip/hip_runtime.h>
#include <hip/hip_bf16.h>

typedef __attribute__((ext_vector_type(8))) __bf16 bf16x8;
typedef __attribute__((ext_vector_type(4))) float f32x4;

#if __has_builtin(__builtin_amdgcn_exp2f)
#define EXP2F(x) __builtin_amdgcn_exp2f(x)
#else
#define EXP2F(x) exp2f(x)
#endif

static constexpr int BB = 8, CC = 64, NN = 4096;
// ws layout (bytes): qfrag[2MB] | kfrag[2MB] | vfrag[4MB]  (total 8MB)
static constexpr size_t QF_OFF = 0;
static constexpr size_t KF_OFF = (size_t)2 << 20;
static constexpr size_t VF_OFF = (size_t)4 << 20;

// Fragment arrays (bf16):
//  qfrag[b][itile(256)][lane][8] : i = itile*16 + (lane&15); qd=lane>>4
//      sections: qd0=qhi, qd1=qlo, qd2=qhi, qd3=0   (q pre-scaled by log2e, +bias)
//  kfrag[b][jt(128)][th(2)][lane][8] : j = jt*32 + th*16 + (lane&15)
//      sections: qd0=khi, qd1=khi, qd2=klo, qd3=0   (+bias)
//  vfrag[b][jt(128)][ct(4)][lane][8] : c = ct*16 + (lane&15); slot r:
//      r<4 -> V[c][jt*32 + 4*qd + r], r>=4 -> V[c][jt*32 + 16 + 4*qd + (r&3)]
//  (jperm matches energy-MFMA C/D layout so exp() results feed PV directly)

__global__ __launch_bounds__(256) void proj_kernel(
    const float* __restrict__ query, const float* __restrict__ value,
    const float* __restrict__ Wq, const float* __restrict__ bq,
    const float* __restrict__ Wk, const float* __restrict__ bk,
    const float* __restrict__ Wv, const float* __restrict__ bv,
    char* __restrict__ ws) {
  __shared__ __bf16 vlds[64][68];   // [px][c], padded row
  __shared__ float  qlds[64][9];    // [px][o], log2e-scaled, +bias
  __shared__ float  klds[64][9];
  const float LOG2E = 1.4426950408889634f;
  int t = threadIdx.x;
  int part = t >> 6, px = t & 63;   // part is wave-uniform
  int blk = blockIdx.x;
  int b = blk >> 6;
  int px0 = (blk & 63) << 6;        // 64 pixels per block
  size_t inbase = (size_t)b * CC * NN + px0 + px;

  float vacc[16];
  #pragma unroll
  for (int o = 0; o < 16; ++o) vacc[o] = bv[part * 16 + o];
  int qko = (part >> 1) << 2;                 // o-offset 0 or 4
  bool isq = (part & 1) == 0;                 // parts 0,2 -> q; 1,3 -> k
  const float* Wqk = isq ? Wq : Wk;
  float qk[4] = {0.f, 0.f, 0.f, 0.f};

  for (int c = 0; c < 64; ++c) {
    float xq = query[inbase + (size_t)c * NN];
    float xv = value[inbase + (size_t)c * NN];
    #pragma unroll
    for (int o = 0; o < 16; ++o) vacc[o] += Wv[(part * 16 + o) * 64 + c] * xv;
    #pragma unroll
    for (int o = 0; o < 4; ++o) qk[o] += Wqk[(qko + o) * 64 + c] * xq;
  }

  #pragma unroll
  for (int o = 0; o < 16; ++o) vlds[px][part * 16 + o] = (__bf16)vacc[o];
  if (isq) {
    #pragma unroll
    for (int o = 0; o < 4; ++o) qlds[px][qko + o] = (qk[o] + bq[qko + o]) * LOG2E;
  } else {
    #pragma unroll
    for (int o = 0; o < 4; ++o) klds[px][qko + o] = qk[o] + bk[qko + o];
  }
  __syncthreads();

  __bf16* qfrag = (__bf16*)(ws + QF_OFF);
  __bf16* kfrag = (__bf16*)(ws + KF_OFF);
  __bf16* vfrag = (__bf16*)(ws + VF_OFF);
  int l = t & 63, cp = l & 15, qd = l >> 4;
  int ct = t >> 6;

  // vfrag: this block covers 2 j-tiles of 32
  #pragma unroll
  for (int jt = 0; jt < 2; ++jt) {
    bf16x8 v8;
    #pragma unroll
    for (int r = 0; r < 8; ++r) {
      int jj = (r < 4) ? (4 * qd + r) : (16 + 4 * qd + (r & 3));
      v8[r] = vlds[jt * 32 + jj][ct * 16 + cp];
    }
    int jtg = (blk & 63) * 2 + jt;
    *(bf16x8*)(vfrag + ((((size_t)b * 128 + jtg) * 4 + ct) * 64 + l) * 8) = v8;
  }
  // kfrag
  {
    int jt = t >> 7, th = (t >> 6) & 1;
    int pxl = jt * 32 + th * 16 + (l & 15);
    bf16x8 k8;
    #pragma unroll
    for (int r = 0; r < 8; ++r) {
      float kv = klds[pxl][r];
      __bf16 hi = (__bf16)kv;
      __bf16 lo = (__bf16)(kv - (float)hi);
      k8[r] = (qd < 2) ? hi : (qd == 2 ? lo : (__bf16)0.f);
    }
    int jtg = (blk & 63) * 2 + jt;
    *(bf16x8*)(kfrag + ((((size_t)b * 128 + jtg) * 2 + th) * 64 + l) * 8) = k8;
  }
  // qfrag: 4 i-tiles of 16 per block
  {
    int il = ct * 16 + (l & 15);
    bf16x8 q8;
    #pragma unroll
    for (int r = 0; r < 8; ++r) {
      float qv = qlds[il][r];
      __bf16 hi = (__bf16)qv;
      __bf16 lo = (__bf16)(qv - (float)hi);
      q8[r] = (qd == 0 || qd == 2) ? hi : (qd == 1 ? lo : (__bf16)0.f);
    }
    int itg = (blk & 63) * 4 + ct;
    *(bf16x8*)(qfrag + (((size_t)b * 256 + itg) * 64 + l) * 8) = q8;
  }
}

// Block: 32 i-rows (two 16-i tiles), 4 waves each take a j-quarter (1024 j = 32 tiles).
// Partial PV accumulators and partial softmax-denominators combine in LDS
// (softmax accumulates linearly before the final divide; no max-subtraction
// needed: |energy| <= ~25 in exp2 domain, well within fp32).
__global__ __launch_bounds__(256, 4) void attn_kernel(
    const char* __restrict__ ws, const float* __restrict__ value,
    float* __restrict__ out) {
  __shared__ float lds_acc[32 * 4 * 64];  // [elem(32)][wave(4)][lane]
  __shared__ float lds_l[8 * 64];         // [(it*4+w)][lane]
  const __bf16* qfrag = (const __bf16*)(ws + QF_OFF);
  const __bf16* kfrag = (const __bf16*)(ws + KF_OFF);
  const __bf16* vfrag = (const __bf16*)(ws + VF_OFF);
  int tid = threadIdx.x;
  int w = tid >> 6, lane = tid & 63, ip = lane & 15, qd = lane >> 4;
  int blk = blockIdx.x;
  int b = blk >> 7;
  int i0 = (blk & 127) << 5;
  int itg0 = (blk & 127) * 2;

  bf16x8 qf[2];
  #pragma unroll
  for (int it = 0; it < 2; ++it)
    qf[it] = *(const bf16x8*)(qfrag + (((size_t)b * 256 + itg0 + it) * 64 + lane) * 8);

  f32x4 acc[4][2];
  #pragma unroll
  for (int ct = 0; ct < 4; ++ct)
    #pragma unroll
    for (int it = 0; it < 2; ++it) acc[ct][it] = (f32x4){0.f, 0.f, 0.f, 0.f};
  float lsum[2] = {0.f, 0.f};

  const __bf16* kb = kfrag + (((size_t)b * 128 + w * 32) * 2 * 64 + lane) * 8;
  const __bf16* vb = vfrag + (((size_t)b * 128 + w * 32) * 4 * 64 + lane) * 8;

  for (int itx = 0; itx < 32; ++itx) {
    bf16x8 kf0 = *(const bf16x8*)(kb);
    bf16x8 kf1 = *(const bf16x8*)(kb + 512);
    bf16x8 vf0 = *(const bf16x8*)(vb);
    bf16x8 vf1 = *(const bf16x8*)(vb + 512);
    bf16x8 vf2 = *(const bf16x8*)(vb + 1024);
    bf16x8 vf3 = *(const bf16x8*)(vb + 1536);
    const f32x4 z = (f32x4){0.f, 0.f, 0.f, 0.f};
    f32x4 e00 = __builtin_amdgcn_mfma_f32_16x16x32_bf16(kf0, qf[0], z, 0, 0, 0);
    f32x4 e01 = __builtin_amdgcn_mfma_f32_16x16x32_bf16(kf1, qf[0], z, 0, 0, 0);
    f32x4 e10 = __builtin_amdgcn_mfma_f32_16x16x32_bf16(kf0, qf[1], z, 0, 0, 0);
    f32x4 e11 = __builtin_amdgcn_mfma_f32_16x16x32_bf16(kf1, qf[1], z, 0, 0, 0);
    bf16x8 pf[2];
    #pragma unroll
    for (int g = 0; g < 4; ++g) {
      float p0 = EXP2F(e00[g]); lsum[0] += p0; pf[0][g] = (__bf16)p0;
      float p1 = EXP2F(e01[g]); lsum[0] += p1; pf[0][4 + g] = (__bf16)p1;
      float p2 = EXP2F(e10[g]); lsum[1] += p2; pf[1][g] = (__bf16)p2;
      float p3 = EXP2F(e11[g]); lsum[1] += p3; pf[1][4 + g] = (__bf16)p3;
    }
    acc[0][0] = __builtin_amdgcn_mfma_f32_16x16x32_bf16(vf0, pf[0], acc[0][0], 0, 0, 0);
    acc[1][0] = __builtin_amdgcn_mfma_f32_16x16x32_bf16(vf1, pf[0], acc[1][0], 0, 0, 0);
    acc[2][0] = __builtin_amdgcn_mfma_f32_16x16x32_bf16(vf2, pf[0], acc[2][0], 0, 0, 0);
    acc[3][0] = __builtin_amdgcn_mfma_f32_16x16x32_bf16(vf3, pf[0], acc[3][0], 0, 0, 0);
    acc[0][1] = __builtin_amdgcn_mfma_f32_16x16x32_bf16(vf0, pf[1], acc[0][1], 0, 0, 0);
    acc[1][1] = __builtin_amdgcn_mfma_f32_16x16x32_bf16(vf1, pf[1], acc[1][1], 0, 0, 0);
    acc[2][1] = __builtin_amdgcn_mfma_f32_16x16x32_bf16(vf2, pf[1], acc[2][1], 0, 0, 0);
    acc[3][1] = __builtin_amdgcn_mfma_f32_16x16x32_bf16(vf3, pf[1], acc[3][1], 0, 0, 0);
    kb += 1024;   // bf16 elements per j-tile step
    vb += 2048;
  }

  #pragma unroll
  for (int it = 0; it < 2; ++it) {
    lsum[it] += __shfl_xor(lsum[it], 16, 64);
    lsum[it] += __shfl_xor(lsum[it], 32, 64);
  }

  #pragma unroll
  for (int ct = 0; ct < 4; ++ct)
    #pragma unroll
    for (int it = 0; it < 2; ++it)
      #pragma unroll
      for (int r = 0; r < 4; ++r) {
        int e = ct * 8 + it * 4 + r;
        lds_acc[(e * 4 + w) * 64 + lane] = acc[ct][it][r];
      }
  lds_l[(0 * 4 + w) * 64 + lane] = lsum[0];
  lds_l[(1 * 4 + w) * 64 + lane] = lsum[1];
  __syncthreads();

  // Epilogue: thread t -> ct = t>>6, lane l. Sum 4 wave-partials, divide, +value.
  int ct = tid >> 6, l = tid & 63;
  #pragma unroll
  for (int it = 0; it < 2; ++it) {
    float ls = 0.f;
    #pragma unroll
    for (int ww = 0; ww < 4; ++ww) ls += lds_l[(it * 4 + ww) * 64 + (l & 15)];
    float inv = 1.0f / ls;
    int n = i0 + it * 16 + (l & 15);
    #pragma unroll
    for (int r = 0; r < 4; ++r) {
      int e = ct * 8 + it * 4 + r;
      float s = 0.f;
      #pragma unroll
      for (int ww = 0; ww < 4; ++ww) s += lds_acc[(e * 4 + ww) * 64 + l];
      int c = ct * 16 + (l >> 4) * 4 + r;
      size_t idx = ((size_t)b * CC + c) * NN + n;
      out[idx] = s * inv + value[idx];
    }
  }
}

extern "C" void kernel_launch(void* const* d_in, const int* in_sizes, int n_in,
                              void* d_out, int out_size, void* d_ws, size_t ws_size,
                              hipStream_t stream) {
  const float* query = (const float*)d_in[0];
  const float* value = (const float*)d_in[1];
  const float* Wq = (const float*)d_in[2];
  const float* bq = (const float*)d_in[3];
  const float* Wk = (const float*)d_in[4];
  const float* bk = (const float*)d_in[5];
  const float* Wv = (const float*)d_in[6];
  const float* bv = (const float*)d_in[7];
  float* out = (float*)d_out;

  proj_kernel<<<512, 256, 0, stream>>>(query, value, Wq, bq, Wk, bk, Wv, bv, (char*)d_ws);
  attn_kernel<<<1024, 256, 0, stream>>>((const char*)d_ws, value, out);
}

// Round 3
// 124.652 us; speedup vs baseline: 2.6952x; 1.2571x over previous
//
#include <hip/hip_runtime.h>
#include <hip/hip_bf16.h>

typedef __attribute__((ext_vector_type(8))) __bf16 bf16x8;
typedef __attribute__((ext_vector_type(4))) float f32x4;

#if __has_builtin(__builtin_amdgcn_exp2f)
#define EXP2F(x) __builtin_amdgcn_exp2f(x)
#else
#define EXP2F(x) exp2f(x)
#endif

static constexpr int BB = 8, CC = 64, NN = 4096;
// ws layout (bytes): qfrag[2MB] | kfrag[2MB] | vfrag[4MB]  (total 8MB)
static constexpr size_t QF_OFF = 0;
static constexpr size_t KF_OFF = (size_t)2 << 20;
static constexpr size_t VF_OFF = (size_t)4 << 20;

// Fragment arrays (bf16):
//  qfrag[b][itile(256)][lane][8] : i = itile*16 + (lane&15); qd=lane>>4
//      sections: qd0=qhi, qd1=qlo, qd2=qhi, qd3=0   (q pre-scaled by log2e, +bias)
//  kfrag[b][jt(128)][th(2)][lane][8] : j = jt*32 + th*16 + (lane&15)
//      sections: qd0=khi, qd1=khi, qd2=klo, qd3=0   (+bias)
//  vfrag[b][jt(128)][ct(4)][lane][8] : c = ct*16 + (lane&15); slot r:
//      r<4 -> V[c][jt*32 + 4*qd + r], r>=4 -> V[c][jt*32 + 16 + 4*qd + (r&3)]
//  (jperm matches energy-MFMA C/D layout so exp() results feed PV directly)

__global__ __launch_bounds__(256) void proj_kernel(
    const float* __restrict__ query, const float* __restrict__ value,
    const float* __restrict__ Wq, const float* __restrict__ bq,
    const float* __restrict__ Wk, const float* __restrict__ bk,
    const float* __restrict__ Wv, const float* __restrict__ bv,
    char* __restrict__ ws) {
  __shared__ __bf16 vlds[64][68];   // [px][c], padded row
  __shared__ float  qlds[64][9];    // [px][o], log2e-scaled, +bias
  __shared__ float  klds[64][9];
  const float LOG2E = 1.4426950408889634f;
  int t = threadIdx.x;
  // readfirstlane makes `part` provably wave-uniform -> all weight addresses
  // become scalar -> s_load on the scalar pipe, FMAs take SGPR operands.
  int part = __builtin_amdgcn_readfirstlane(t >> 6);
  int px = t & 63;
  int blk = blockIdx.x;
  int b = blk >> 6;
  int px0 = (blk & 63) << 6;        // 64 pixels per block
  size_t inbase = (size_t)b * CC * NN + px0 + px;

  int qko = (part >> 1) << 2;                 // o-offset 0 or 4
  bool isq = (part & 1) == 0;                 // parts 0,2 -> q; 1,3 -> k
  const float* __restrict__ Wqk = isq ? Wq : Wk;

  // ---- phase A: q/k projection (inputs register-resident, weights scalar)
  float xq[64];
  #pragma unroll
  for (int c = 0; c < 64; ++c) xq[c] = query[inbase + (size_t)c * NN];
  float qk[4] = {0.f, 0.f, 0.f, 0.f};
  #pragma unroll
  for (int c = 0; c < 64; ++c) {
    #pragma unroll
    for (int o = 0; o < 4; ++o) qk[o] += Wqk[(qko + o) * 64 + c] * xq[c];
  }
  if (isq) {
    #pragma unroll
    for (int o = 0; o < 4; ++o) qlds[px][qko + o] = (qk[o] + bq[qko + o]) * LOG2E;
  } else {
    #pragma unroll
    for (int o = 0; o < 4; ++o) klds[px][qko + o] = qk[o] + bk[qko + o];
  }

  // ---- phase B: v projection (16 output channels per part)
  float xv[64];
  #pragma unroll
  for (int c = 0; c < 64; ++c) xv[c] = value[inbase + (size_t)c * NN];
  float vacc[16];
  #pragma unroll
  for (int o = 0; o < 16; ++o) vacc[o] = bv[part * 16 + o];
  #pragma unroll
  for (int c = 0; c < 64; ++c) {
    #pragma unroll
    for (int o = 0; o < 16; ++o) vacc[o] += Wv[(part * 16 + o) * 64 + c] * xv[c];
  }
  #pragma unroll
  for (int o = 0; o < 16; ++o) vlds[px][part * 16 + o] = (__bf16)vacc[o];
  __syncthreads();

  // ---- fragment building (layouts documented above)
  __bf16* qfrag = (__bf16*)(ws + QF_OFF);
  __bf16* kfrag = (__bf16*)(ws + KF_OFF);
  __bf16* vfrag = (__bf16*)(ws + VF_OFF);
  int l = t & 63, cp = l & 15, qd = l >> 4;
  int ct = t >> 6;

  #pragma unroll
  for (int jt = 0; jt < 2; ++jt) {
    bf16x8 v8;
    #pragma unroll
    for (int r = 0; r < 8; ++r) {
      int jj = (r < 4) ? (4 * qd + r) : (16 + 4 * qd + (r & 3));
      v8[r] = vlds[jt * 32 + jj][ct * 16 + cp];
    }
    int jtg = (blk & 63) * 2 + jt;
    *(bf16x8*)(vfrag + ((((size_t)b * 128 + jtg) * 4 + ct) * 64 + l) * 8) = v8;
  }
  {
    int jt = t >> 7, th = (t >> 6) & 1;
    int pxl = jt * 32 + th * 16 + (l & 15);
    bf16x8 k8;
    #pragma unroll
    for (int r = 0; r < 8; ++r) {
      float kv = klds[pxl][r];
      __bf16 hi = (__bf16)kv;
      __bf16 lo = (__bf16)(kv - (float)hi);
      k8[r] = (qd < 2) ? hi : (qd == 2 ? lo : (__bf16)0.f);
    }
    int jtg = (blk & 63) * 2 + jt;
    *(bf16x8*)(kfrag + ((((size_t)b * 128 + jtg) * 2 + th) * 64 + l) * 8) = k8;
  }
  {
    int il = ct * 16 + (l & 15);
    bf16x8 q8;
    #pragma unroll
    for (int r = 0; r < 8; ++r) {
      float qv = qlds[il][r];
      __bf16 hi = (__bf16)qv;
      __bf16 lo = (__bf16)(qv - (float)hi);
      q8[r] = (qd == 0 || qd == 2) ? hi : (qd == 1 ? lo : (__bf16)0.f);
    }
    int itg = (blk & 63) * 4 + ct;
    *(bf16x8*)(qfrag + (((size_t)b * 256 + itg) * 64 + l) * 8) = q8;
  }
}

// Block: 64 i-rows (four 16-i tiles), 4 waves each take a j-quarter (1024 j = 32 tiles).
// K/V-frag reads are amortized over 64 rows (halves L2 traffic vs 32-row blocks).
// Partial PV accumulators + denominators combine in LDS; epilogue in two passes
// (it-pairs) so lds_acc stays at 32 KB. No max-subtraction needed: |energy|
// (exp2-domain) <= ~25, exp and row-sums stay well inside fp32.
__global__ __launch_bounds__(256, 2) void attn_kernel(
    const char* __restrict__ ws, const float* __restrict__ value,
    float* __restrict__ out) {
  __shared__ float lds_acc[32 * 4 * 64];  // [elem(32)][wave(4)][lane] — reused 2x
  __shared__ float lds_l[16 * 64];        // [(it*4+w)][lane]
  const __bf16* qfrag = (const __bf16*)(ws + QF_OFF);
  const __bf16* kfrag = (const __bf16*)(ws + KF_OFF);
  const __bf16* vfrag = (const __bf16*)(ws + VF_OFF);
  int tid = threadIdx.x;
  int w = tid >> 6, lane = tid & 63;
  int blk = blockIdx.x;
  int b = blk >> 6;
  int i0 = (blk & 63) << 6;
  int itg0 = (blk & 63) * 4;

  bf16x8 qf[4];
  #pragma unroll
  for (int it = 0; it < 4; ++it)
    qf[it] = *(const bf16x8*)(qfrag + (((size_t)b * 256 + itg0 + it) * 64 + lane) * 8);

  f32x4 acc[4][4];
  #pragma unroll
  for (int ct = 0; ct < 4; ++ct)
    #pragma unroll
    for (int it = 0; it < 4; ++it) acc[ct][it] = (f32x4){0.f, 0.f, 0.f, 0.f};
  float lsum[4] = {0.f, 0.f, 0.f, 0.f};

  const __bf16* kb = kfrag + (((size_t)b * 128 + w * 32) * 2 * 64 + lane) * 8;
  const __bf16* vb = vfrag + (((size_t)b * 128 + w * 32) * 4 * 64 + lane) * 8;

  for (int itx = 0; itx < 32; ++itx) {
    bf16x8 kf0 = *(const bf16x8*)(kb);
    bf16x8 kf1 = *(const bf16x8*)(kb + 512);
    bf16x8 vf0 = *(const bf16x8*)(vb);
    bf16x8 vf1 = *(const bf16x8*)(vb + 512);
    bf16x8 vf2 = *(const bf16x8*)(vb + 1024);
    bf16x8 vf3 = *(const bf16x8*)(vb + 1536);
    const f32x4 z = (f32x4){0.f, 0.f, 0.f, 0.f};
    bf16x8 pf[4];
    #pragma unroll
    for (int it = 0; it < 4; ++it) {
      f32x4 e0 = __builtin_amdgcn_mfma_f32_16x16x32_bf16(kf0, qf[it], z, 0, 0, 0);
      f32x4 e1 = __builtin_amdgcn_mfma_f32_16x16x32_bf16(kf1, qf[it], z, 0, 0, 0);
      #pragma unroll
      for (int g = 0; g < 4; ++g) {
        float p0 = EXP2F(e0[g]); lsum[it] += p0; pf[it][g] = (__bf16)p0;
        float p1 = EXP2F(e1[g]); lsum[it] += p1; pf[it][4 + g] = (__bf16)p1;
      }
    }
    #pragma unroll
    for (int it = 0; it < 4; ++it) {
      acc[0][it] = __builtin_amdgcn_mfma_f32_16x16x32_bf16(vf0, pf[it], acc[0][it], 0, 0, 0);
      acc[1][it] = __builtin_amdgcn_mfma_f32_16x16x32_bf16(vf1, pf[it], acc[1][it], 0, 0, 0);
      acc[2][it] = __builtin_amdgcn_mfma_f32_16x16x32_bf16(vf2, pf[it], acc[2][it], 0, 0, 0);
      acc[3][it] = __builtin_amdgcn_mfma_f32_16x16x32_bf16(vf3, pf[it], acc[3][it], 0, 0, 0);
    }
    kb += 1024;   // bf16 elements per j-tile step
    vb += 2048;
  }

  #pragma unroll
  for (int it = 0; it < 4; ++it) {
    lsum[it] += __shfl_xor(lsum[it], 16, 64);
    lsum[it] += __shfl_xor(lsum[it], 32, 64);
    lds_l[(it * 4 + w) * 64 + lane] = lsum[it];
  }

  int ect = tid >> 6, l = tid & 63;
  #pragma unroll
  for (int p = 0; p < 2; ++p) {
    if (p) __syncthreads();   // protect lds_acc from overwrite before reads done
    #pragma unroll
    for (int ct = 0; ct < 4; ++ct)
      #pragma unroll
      for (int itl = 0; itl < 2; ++itl)
        #pragma unroll
        for (int r = 0; r < 4; ++r) {
          int e = ct * 8 + itl * 4 + r;
          lds_acc[(e * 4 + w) * 64 + lane] = acc[ct][2 * p + itl][r];
        }
    __syncthreads();
    #pragma unroll
    for (int itl = 0; itl < 2; ++itl) {
      int it = 2 * p + itl;
      float ls = 0.f;
      #pragma unroll
      for (int ww = 0; ww < 4; ++ww) ls += lds_l[(it * 4 + ww) * 64 + (l & 15)];
      float inv = 1.0f / ls;
      int n = i0 + it * 16 + (l & 15);
      #pragma unroll
      for (int r = 0; r < 4; ++r) {
        int e = ect * 8 + itl * 4 + r;
        float s = 0.f;
        #pragma unroll
        for (int ww = 0; ww < 4; ++ww) s += lds_acc[(e * 4 + ww) * 64 + l];
        int c = ect * 16 + (l >> 4) * 4 + r;
        size_t idx = ((size_t)b * CC + c) * NN + n;
        out[idx] = s * inv + value[idx];
      }
    }
  }
}

extern "C" void kernel_launch(void* const* d_in, const int* in_sizes, int n_in,
                              void* d_out, int out_size, void* d_ws, size_t ws_size,
                              hipStream_t stream) {
  const float* query = (const float*)d_in[0];
  const float* value = (const float*)d_in[1];
  const float* Wq = (const float*)d_in[2];
  const float* bq = (const float*)d_in[3];
  const float* Wk = (const float*)d_in[4];
  const float* bk = (const float*)d_in[5];
  const float* Wv = (const float*)d_in[6];
  const float* bv = (const float*)d_in[7];
  float* out = (float*)d_out;

  proj_kernel<<<512, 256, 0, stream>>>(query, value, Wq, bq, Wk, bk, Wv, bv, (char*)d_ws);
  attn_kernel<<<512, 256, 0, stream>>>((const char*)d_ws, value, out);
}